// Round 1
// baseline (191.955 us; speedup 1.0000x reference)
//
#include <hip/hip_runtime.h>
#include <float.h>
#include <math.h>

#define N 512
#define E 16384
#define D 1280
#define LMDIM 1024
#define NFDIM 256
#define M 64

// h[i][j] = j < 1024 ? lm_embedding[0, i+1, j] : node_feat[i, j-1024]
__device__ __forceinline__ float h_val(const float* __restrict__ lm,
                                       const float* __restrict__ nf,
                                       int i, int j) {
  return (j < LMDIM) ? lm[(i + 1) * LMDIM + j] : nf[i * NFDIM + (j - LMDIM)];
}

// ---------------- CSR build ----------------
__global__ __launch_bounds__(256) void hist_kernel(const int* __restrict__ dst,
                                                   int* __restrict__ counts) {
  int e = blockIdx.x * 256 + threadIdx.x;
  atomicAdd(&counts[dst[e]], 1);
}

__global__ __launch_bounds__(512) void scan_kernel(const int* __restrict__ counts,
                                                   int* __restrict__ offsets,
                                                   int* __restrict__ cursor) {
  __shared__ int s[N];
  int t = threadIdx.x;
  int c = counts[t];
  s[t] = c;
  __syncthreads();
  for (int off = 1; off < N; off <<= 1) {
    int v = (t >= off) ? s[t - off] : 0;
    __syncthreads();
    s[t] += v;
    __syncthreads();
  }
  offsets[t + 1] = s[t];      // inclusive -> offsets[1..N]
  if (t == 0) offsets[0] = 0;
  cursor[t] = s[t] - c;       // exclusive prefix = write cursor
}

__global__ __launch_bounds__(256) void scatter_kernel(const int* __restrict__ src,
                                                      const int* __restrict__ dst,
                                                      const float* __restrict__ ew,
                                                      int* __restrict__ cursor,
                                                      int* __restrict__ src_s,
                                                      float* __restrict__ ew_s) {
  int e = blockIdx.x * 256 + threadIdx.x;
  int d = dst[e];
  int pos = atomicAdd(&cursor[d], 1);
  src_s[pos] = src[e];
  ew_s[pos] = ew[e];
}

// ---------------- segment-max + A = h + neigh ----------------
__global__ __launch_bounds__(256) void neigh_kernel(const float* __restrict__ lm,
                                                    const float* __restrict__ nf,
                                                    const int* __restrict__ offsets,
                                                    const int* __restrict__ src_s,
                                                    const float* __restrict__ ew_s,
                                                    float* __restrict__ A) {
  int n = blockIdx.x;
  int t = threadIdx.x;
  int beg = offsets[n], end = offsets[n + 1];
  float m[5];
#pragma unroll
  for (int i = 0; i < 5; ++i) m[i] = -FLT_MAX;
  for (int e = beg; e < end; ++e) {
    int s = src_s[e];
    float w = ew_s[e];
#pragma unroll
    for (int i = 0; i < 5; ++i) {
      int d = t + 256 * i;
      m[i] = fmaxf(m[i], h_val(lm, nf, s, d) * w);
    }
  }
  bool has = (end > beg);  // isolated node -> neigh = 0 (DGL semantics)
#pragma unroll
  for (int i = 0; i < 5; ++i) {
    int d = t + 256 * i;
    A[n * D + d] = h_val(lm, nf, n, d) + (has ? m[i] : 0.0f);
  }
}

// ---------------- GEMM: NO = A @ W_g + b_g + h ----------------
#define BM 64
#define BN 64
#define BK 16
__global__ __launch_bounds__(256) void gemm_kernel(const float* __restrict__ A,
                                                   const float* __restrict__ W,
                                                   const float* __restrict__ bg,
                                                   const float* __restrict__ lm,
                                                   const float* __restrict__ nf,
                                                   float* __restrict__ C) {
  __shared__ __align__(16) float As[BK][BM + 4];  // +4 pad: keeps 16B align, breaks conflicts
  __shared__ __align__(16) float Ws[BK][BN + 4];
  int tid = threadIdx.x;
  int tx = tid & 15, ty = tid >> 4;
  int rowBase = blockIdx.y * BM;
  int colBase = blockIdx.x * BN;
  float acc[4][4] = {};

  // A-tile load: thread loads float4 along k; ar=row 0..63, ak=k quad
  int ar = tid >> 2;
  int ak = (tid & 3) << 2;
  // W-tile load: wk=k row 0..15, wc=col quad
  int wk = tid >> 4;
  int wc = (tid & 15) << 2;

  for (int k0 = 0; k0 < D; k0 += BK) {
    float4 av = *(const float4*)&A[(rowBase + ar) * D + k0 + ak];
    float4 wv = *(const float4*)&W[(k0 + wk) * D + colBase + wc];
    __syncthreads();
    As[ak + 0][ar] = av.x;
    As[ak + 1][ar] = av.y;
    As[ak + 2][ar] = av.z;
    As[ak + 3][ar] = av.w;
    *(float4*)&Ws[wk][wc] = wv;
    __syncthreads();
#pragma unroll
    for (int k = 0; k < BK; ++k) {
      float4 a = *(const float4*)&As[k][ty * 4];
      float4 b = *(const float4*)&Ws[k][tx * 4];
      acc[0][0] += a.x * b.x; acc[0][1] += a.x * b.y; acc[0][2] += a.x * b.z; acc[0][3] += a.x * b.w;
      acc[1][0] += a.y * b.x; acc[1][1] += a.y * b.y; acc[1][2] += a.y * b.z; acc[1][3] += a.y * b.w;
      acc[2][0] += a.z * b.x; acc[2][1] += a.z * b.y; acc[2][2] += a.z * b.z; acc[2][3] += a.z * b.w;
      acc[3][0] += a.w * b.x; acc[3][1] += a.w * b.y; acc[3][2] += a.w * b.z; acc[3][3] += a.w * b.w;
    }
  }

#pragma unroll
  for (int i = 0; i < 4; ++i) {
    int r = rowBase + ty * 4 + i;
#pragma unroll
    for (int j = 0; j < 4; ++j) {
      int c = colBase + tx * 4 + j;
      C[r * D + c] = acc[i][j] + bg[c] + h_val(lm, nf, r, c);
    }
  }
}

// ---------------- p = NO @ W_d ----------------
__global__ __launch_bounds__(256) void p_kernel(const float* __restrict__ NO,
                                                const float* __restrict__ Wd,
                                                float* __restrict__ p) {
  int i = blockIdx.x, t = threadIdx.x;
  float acc = 0.f;
#pragma unroll
  for (int j = 0; j < 5; ++j) {
    int k = t + 256 * j;
    acc += NO[i * D + k] * Wd[k];
  }
  __shared__ float s[256];
  s[t] = acc;
  __syncthreads();
  for (int off = 128; off > 0; off >>= 1) {
    if (t < off) s[t] += s[t + off];
    __syncthreads();
  }
  if (t == 0) p[i] = s[0];
}

// ---------------- dis_pred[i,j] = sigmoid(p[j]-p[i]+b_d) ----------------
__global__ __launch_bounds__(256) void dis_kernel(const float* __restrict__ p,
                                                  const float* __restrict__ bd,
                                                  float* __restrict__ out) {
  int idx = blockIdx.x * 256 + threadIdx.x;
  int i = idx >> 9;
  int j = idx & 511;
  float v = p[j] - p[i] + bd[0];
  out[idx] = 1.0f / (1.0f + expf(-v));
}

// ---------------- mask_pred = tanh(NO[mask] @ W_m + b_m) ----------------
__global__ __launch_bounds__(256) void mask_kernel(const float* __restrict__ NO,
                                                   const int* __restrict__ mask_index,
                                                   const float* __restrict__ Wm,
                                                   const float* __restrict__ bm,
                                                   float* __restrict__ out) {
  int b = blockIdx.x, t = threadIdx.x;
  int row = mask_index[b];
  float a0 = 0.f, a1 = 0.f;
#pragma unroll
  for (int j = 0; j < 5; ++j) {
    int k = t + 256 * j;
    float v = NO[row * D + k];
    a0 += v * Wm[k * 2 + 0];
    a1 += v * Wm[k * 2 + 1];
  }
  __shared__ float s0[256], s1[256];
  s0[t] = a0;
  s1[t] = a1;
  __syncthreads();
  for (int off = 128; off > 0; off >>= 1) {
    if (t < off) {
      s0[t] += s0[t + off];
      s1[t] += s1[t + off];
    }
    __syncthreads();
  }
  if (t == 0) {
    out[(size_t)N * N + b * 2 + 0] = tanhf(s0[0] + bm[0]);
    out[(size_t)N * N + b * 2 + 1] = tanhf(s1[0] + bm[1]);
  }
}

extern "C" void kernel_launch(void* const* d_in, const int* in_sizes, int n_in,
                              void* d_out, int out_size, void* d_ws, size_t ws_size,
                              hipStream_t stream) {
  const float* lm = (const float*)d_in[0];   // (1, 514, 1024)
  const float* nf = (const float*)d_in[1];   // (512, 256)
  const float* ew = (const float*)d_in[2];   // (E, 1)
  const int* src = (const int*)d_in[3];      // (E,)
  const int* dst = (const int*)d_in[4];      // (E,)
  const int* mask_index = (const int*)d_in[5];  // (M,)
  const float* Wg = (const float*)d_in[6];   // (D, D)
  const float* bg = (const float*)d_in[7];   // (D,)
  const float* Wd = (const float*)d_in[8];   // (D, 1)
  const float* bd = (const float*)d_in[9];   // (1,)
  const float* Wm = (const float*)d_in[10];  // (D, 2)
  const float* bm = (const float*)d_in[11];  // (2,)
  float* out = (float*)d_out;

  char* w = (char*)d_ws;
  float* A       = (float*)(w);                       // 512*1280*4 = 2,621,440
  float* NO      = (float*)(w + 2621440);             // 2,621,440
  float* p       = (float*)(w + 5242880);             // 2,048
  int* counts    = (int*)(w + 5244928);               // 2,048
  int* offsets   = (int*)(w + 5246976);               // 2,052 (pad to 2,064)
  int* cursor    = (int*)(w + 5249040);               // 2,048
  int* src_s     = (int*)(w + 5251088);               // 65,536
  float* ew_s    = (float*)(w + 5316624);             // 65,536  (end 5,382,160)

  hipMemsetAsync(counts, 0, N * sizeof(int), stream);
  hist_kernel<<<E / 256, 256, 0, stream>>>(dst, counts);
  scan_kernel<<<1, 512, 0, stream>>>(counts, offsets, cursor);
  scatter_kernel<<<E / 256, 256, 0, stream>>>(src, dst, ew, cursor, src_s, ew_s);
  neigh_kernel<<<N, 256, 0, stream>>>(lm, nf, offsets, src_s, ew_s, A);
  gemm_kernel<<<dim3(D / BN, N / BM), 256, 0, stream>>>(A, Wg, bg, lm, nf, NO);
  p_kernel<<<N, 256, 0, stream>>>(NO, Wd, p);
  mask_kernel<<<M, 256, 0, stream>>>(NO, mask_index, Wm, bm, out);
  dis_kernel<<<(N * N) / 256, 256, 0, stream>>>(p, bd, out);
}

// Round 2
// 165.763 us; speedup vs baseline: 1.1580x; 1.1580x over previous
//
#include <hip/hip_runtime.h>
#include <float.h>
#include <math.h>

#define N 512
#define E 16384
#define D 1280
#define LMDIM 1024
#define NFDIM 256
#define M 64

typedef __attribute__((ext_vector_type(8))) short s8v;   // 8 bf16 operand (4 VGPRs)
typedef __attribute__((ext_vector_type(4))) float f4v;   // 4 fp32 acc

// ---------- bf16 helpers ----------
__device__ __forceinline__ unsigned short f2bf(float x) {
  unsigned u = __float_as_uint(x);
  unsigned r = (u + 0x7fffu + ((u >> 16) & 1u)) >> 16;   // RNE
  return (unsigned short)r;
}
__device__ __forceinline__ float bf2f(unsigned short h) {
  return __uint_as_float(((unsigned)h) << 16);
}

// h[i][j] = j < 1024 ? lm[0, i+1, j] : nf[i, j-1024]
__device__ __forceinline__ float h_val(const float* __restrict__ lm,
                                       const float* __restrict__ nf,
                                       int i, int j) {
  return (j < LMDIM) ? lm[(i + 1) * LMDIM + j] : nf[i * NFDIM + (j - LMDIM)];
}
__device__ __forceinline__ float4 h_vec4(const float* __restrict__ lm,
                                         const float* __restrict__ nf,
                                         int i, int t) {  // t = col/4, 0..319
  return (t < 256) ? *(const float4*)&lm[(i + 1) * LMDIM + t * 4]
                   : *(const float4*)&nf[i * NFDIM + (t - 256) * 4];
}

// =================== FAST PATH ===================

// ---- fused CSR build: histogram + scan + scatter in one block ----
__global__ __launch_bounds__(1024) void csr_kernel(const int* __restrict__ src,
                                                   const int* __restrict__ dst,
                                                   const float* __restrict__ ew,
                                                   int* __restrict__ offsets,
                                                   int* __restrict__ src_s,
                                                   float* __restrict__ ew_s) {
  __shared__ int cnt[N];
  __shared__ int scn[N];
  __shared__ int cur[N];
  int t = threadIdx.x;
  if (t < N) cnt[t] = 0;
  __syncthreads();
  for (int e = t; e < E; e += 1024) atomicAdd(&cnt[dst[e]], 1);
  __syncthreads();
  if (t < N) scn[t] = cnt[t];
  __syncthreads();
  for (int off = 1; off < N; off <<= 1) {
    int v = (t < N && t >= off) ? scn[t - off] : 0;
    __syncthreads();
    if (t < N) scn[t] += v;
    __syncthreads();
  }
  if (t < N) {
    offsets[t + 1] = scn[t];
    if (t == 0) offsets[0] = 0;
    cur[t] = scn[t] - cnt[t];
  }
  __syncthreads();
  for (int e = t; e < E; e += 1024) {
    int d = dst[e];
    int pos = atomicAdd(&cur[d], 1);
    src_s[pos] = src[e];
    ew_s[pos] = ew[e];
  }
}

// ---- W_g transpose + bf16 hi/lo split: Wt[n][k] = W[k][n] ----
__global__ __launch_bounds__(256) void convw_kernel(const float* __restrict__ W,
                                                    unsigned short* __restrict__ WtHi,
                                                    unsigned short* __restrict__ WtLo) {
  __shared__ float T[32][33];
  int bx = blockIdx.x, by = blockIdx.y;      // bx: n-tile, by: k-tile
  int c = threadIdx.x & 31, r0 = threadIdx.x >> 5;
#pragma unroll
  for (int rr = 0; rr < 4; ++rr) {
    int r = r0 + rr * 8;
    T[r][c] = W[(by * 32 + r) * D + bx * 32 + c];
  }
  __syncthreads();
#pragma unroll
  for (int rr = 0; rr < 4; ++rr) {
    int rn = r0 + rr * 8;                    // n within tile
    float v = T[c][rn];                      // = W[by*32+c][bx*32+rn]
    unsigned short hi = f2bf(v);
    unsigned short lo = f2bf(v - bf2f(hi));
    size_t o = (size_t)(bx * 32 + rn) * D + by * 32 + c;
    WtHi[o] = hi;
    WtLo[o] = lo;
  }
}

// ---- segment-max + A = h + neigh, emitted as bf16 hi/lo ----
__global__ __launch_bounds__(320) void neigh_kernel(const float* __restrict__ lm,
                                                    const float* __restrict__ nf,
                                                    const int* __restrict__ offsets,
                                                    const int* __restrict__ src_s,
                                                    const float* __restrict__ ew_s,
                                                    unsigned short* __restrict__ AHi,
                                                    unsigned short* __restrict__ ALo) {
  int n = blockIdx.x;
  int t = threadIdx.x;                       // 0..319, handles cols t*4..t*4+3
  int beg = offsets[n], end = offsets[n + 1];
  float4 m = make_float4(-FLT_MAX, -FLT_MAX, -FLT_MAX, -FLT_MAX);
  for (int e = beg; e < end; ++e) {
    int s = src_s[e];
    float w = ew_s[e];
    float4 v = h_vec4(lm, nf, s, t);
    m.x = fmaxf(m.x, v.x * w);
    m.y = fmaxf(m.y, v.y * w);
    m.z = fmaxf(m.z, v.z * w);
    m.w = fmaxf(m.w, v.w * w);
  }
  bool has = (end > beg);
  float4 hv = h_vec4(lm, nf, n, t);
  float4 a;
  a.x = hv.x + (has ? m.x : 0.0f);
  a.y = hv.y + (has ? m.y : 0.0f);
  a.z = hv.z + (has ? m.z : 0.0f);
  a.w = hv.w + (has ? m.w : 0.0f);
  ushort4 hi, lo;
  hi.x = f2bf(a.x); lo.x = f2bf(a.x - bf2f(hi.x));
  hi.y = f2bf(a.y); lo.y = f2bf(a.y - bf2f(hi.y));
  hi.z = f2bf(a.z); lo.z = f2bf(a.z - bf2f(hi.z));
  hi.w = f2bf(a.w); lo.w = f2bf(a.w - bf2f(hi.w));
  size_t o = (size_t)n * D + t * 4;
  *(ushort4*)&AHi[o] = hi;
  *(ushort4*)&ALo[o] = lo;
}

// ---- MFMA GEMM: NO = A @ W_g + b_g + h ; fused p += NO @ W_d ----
__global__ __launch_bounds__(256) void gemm_mfma_kernel(const unsigned short* __restrict__ AHi,
                                                        const unsigned short* __restrict__ ALo,
                                                        const unsigned short* __restrict__ WtHi,
                                                        const unsigned short* __restrict__ WtLo,
                                                        const float* __restrict__ bg,
                                                        const float* __restrict__ Wd,
                                                        const float* __restrict__ lm,
                                                        const float* __restrict__ nf,
                                                        float* __restrict__ NO,
                                                        float* __restrict__ p) {
  // LDS tiles: rows = m or n (64), cols = k (32), pad to 40 shorts (80 B, 16B-aligned)
  __shared__ __align__(16) short Ah[64][40];
  __shared__ __align__(16) short Al[64][40];
  __shared__ __align__(16) short Bh[64][40];
  __shared__ __align__(16) short Bl[64][40];

  int tid = threadIdx.x;
  int rowBase = blockIdx.y * 64;
  int colBase = blockIdx.x * 64;

  int sr = tid >> 2;                // staging row 0..63
  int sq = (tid & 3) << 3;          // staging k-offset in shorts (0,8,16,24)

  int w = tid >> 6;                 // wave 0..3 -> rows w*16..w*16+15
  int L = tid & 63;
  int q = L >> 4;                   // quad
  int c = L & 15;

  f4v acc[4];
#pragma unroll
  for (int i = 0; i < 4; ++i) acc[i] = (f4v){0.f, 0.f, 0.f, 0.f};

  const size_t aOff = (size_t)(rowBase + sr) * D + sq;
  const size_t bOff = (size_t)(colBase + sr) * D + sq;

  for (int k0 = 0; k0 < D; k0 += 32) {
    s8v va = *(const s8v*)&AHi[aOff + k0];
    s8v vl = *(const s8v*)&ALo[aOff + k0];
    s8v vb = *(const s8v*)&WtHi[bOff + k0];
    s8v vm = *(const s8v*)&WtLo[bOff + k0];
    __syncthreads();
    *(s8v*)&Ah[sr][sq] = va;
    *(s8v*)&Al[sr][sq] = vl;
    *(s8v*)&Bh[sr][sq] = vb;
    *(s8v*)&Bl[sr][sq] = vm;
    __syncthreads();

    s8v ah = *(const s8v*)&Ah[w * 16 + c][q * 8];
    s8v al = *(const s8v*)&Al[w * 16 + c][q * 8];
#pragma unroll
    for (int ct = 0; ct < 4; ++ct) {
      s8v bh = *(const s8v*)&Bh[ct * 16 + c][q * 8];
      s8v bl = *(const s8v*)&Bl[ct * 16 + c][q * 8];
      acc[ct] = __builtin_amdgcn_mfma_f32_16x16x32_bf16(ah, bh, acc[ct], 0, 0, 0);
      acc[ct] = __builtin_amdgcn_mfma_f32_16x16x32_bf16(al, bh, acc[ct], 0, 0, 0);
      acc[ct] = __builtin_amdgcn_mfma_f32_16x16x32_bf16(ah, bl, acc[ct], 0, 0, 0);
    }
  }

  // epilogue: C/D layout row=(q*4+r), col=c within 16x16 tile
  float pp[4] = {0.f, 0.f, 0.f, 0.f};
#pragma unroll
  for (int r = 0; r < 4; ++r) {
    int row = rowBase + w * 16 + q * 4 + r;
#pragma unroll
    for (int ct = 0; ct < 4; ++ct) {
      int col = colBase + ct * 16 + c;
      float v = acc[ct][r] + bg[col] + h_val(lm, nf, row, col);
      NO[(size_t)row * D + col] = v;
      pp[r] += v * Wd[col];
    }
  }
  // reduce pp over the 16 lanes of the quad (bits 0..3)
#pragma unroll
  for (int r = 0; r < 4; ++r) {
    pp[r] += __shfl_xor(pp[r], 1);
    pp[r] += __shfl_xor(pp[r], 2);
    pp[r] += __shfl_xor(pp[r], 4);
    pp[r] += __shfl_xor(pp[r], 8);
  }
  if (c == 0) {
#pragma unroll
    for (int r = 0; r < 4; ++r) {
      atomicAdd(&p[rowBase + w * 16 + q * 4 + r], pp[r]);
    }
  }
}

// ---- dis_pred[i,j] = sigmoid(p[j]-p[i]+b_d), float4 ----
__global__ __launch_bounds__(256) void dis4_kernel(const float* __restrict__ p,
                                                   const float* __restrict__ bd,
                                                   float* __restrict__ out) {
  int idx = blockIdx.x * 256 + threadIdx.x;  // 0..65535
  int i = idx >> 7;
  int j4 = (idx & 127) * 4;
  float pi = p[i];
  float b = bd[0];
  float4 pj = *(const float4*)&p[j4];
  float4 o;
  o.x = 1.0f / (1.0f + expf(-(pj.x - pi + b)));
  o.y = 1.0f / (1.0f + expf(-(pj.y - pi + b)));
  o.z = 1.0f / (1.0f + expf(-(pj.z - pi + b)));
  o.w = 1.0f / (1.0f + expf(-(pj.w - pi + b)));
  *(float4*)&out[(size_t)i * N + j4] = o;
}

// ---- mask_pred = tanh(NO[mask] @ W_m + b_m) ----
__global__ __launch_bounds__(256) void mask_kernel(const float* __restrict__ NO,
                                                   const int* __restrict__ mask_index,
                                                   const float* __restrict__ Wm,
                                                   const float* __restrict__ bm,
                                                   float* __restrict__ out) {
  int b = blockIdx.x, t = threadIdx.x;
  int row = mask_index[b];
  float a0 = 0.f, a1 = 0.f;
#pragma unroll
  for (int j = 0; j < 5; ++j) {
    int k = t + 256 * j;
    float v = NO[(size_t)row * D + k];
    a0 += v * Wm[k * 2 + 0];
    a1 += v * Wm[k * 2 + 1];
  }
  __shared__ float s0[256], s1[256];
  s0[t] = a0;
  s1[t] = a1;
  __syncthreads();
  for (int off = 128; off > 0; off >>= 1) {
    if (t < off) {
      s0[t] += s0[t + off];
      s1[t] += s1[t + off];
    }
    __syncthreads();
  }
  if (t == 0) {
    out[(size_t)N * N + b * 2 + 0] = tanhf(s0[0] + bm[0]);
    out[(size_t)N * N + b * 2 + 1] = tanhf(s1[0] + bm[1]);
  }
}

// =================== FALLBACK PATH (round-1 fp32, needs 5.4 MB ws) ===================

__global__ __launch_bounds__(256) void hist_kernel(const int* __restrict__ dst,
                                                   int* __restrict__ counts) {
  int e = blockIdx.x * 256 + threadIdx.x;
  atomicAdd(&counts[dst[e]], 1);
}

__global__ __launch_bounds__(512) void scan_kernel(const int* __restrict__ counts,
                                                   int* __restrict__ offsets,
                                                   int* __restrict__ cursor) {
  __shared__ int s[N];
  int t = threadIdx.x;
  int cc = counts[t];
  s[t] = cc;
  __syncthreads();
  for (int off = 1; off < N; off <<= 1) {
    int v = (t >= off) ? s[t - off] : 0;
    __syncthreads();
    s[t] += v;
    __syncthreads();
  }
  offsets[t + 1] = s[t];
  if (t == 0) offsets[0] = 0;
  cursor[t] = s[t] - cc;
}

__global__ __launch_bounds__(256) void scatter_kernel(const int* __restrict__ src,
                                                      const int* __restrict__ dst,
                                                      const float* __restrict__ ew,
                                                      int* __restrict__ cursor,
                                                      int* __restrict__ src_s,
                                                      float* __restrict__ ew_s) {
  int e = blockIdx.x * 256 + threadIdx.x;
  int d = dst[e];
  int pos = atomicAdd(&cursor[d], 1);
  src_s[pos] = src[e];
  ew_s[pos] = ew[e];
}

__global__ __launch_bounds__(256) void neigh_f32_kernel(const float* __restrict__ lm,
                                                        const float* __restrict__ nf,
                                                        const int* __restrict__ offsets,
                                                        const int* __restrict__ src_s,
                                                        const float* __restrict__ ew_s,
                                                        float* __restrict__ A) {
  int n = blockIdx.x;
  int t = threadIdx.x;
  int beg = offsets[n], end = offsets[n + 1];
  float m[5];
#pragma unroll
  for (int i = 0; i < 5; ++i) m[i] = -FLT_MAX;
  for (int e = beg; e < end; ++e) {
    int s = src_s[e];
    float w = ew_s[e];
#pragma unroll
    for (int i = 0; i < 5; ++i) {
      int d = t + 256 * i;
      m[i] = fmaxf(m[i], h_val(lm, nf, s, d) * w);
    }
  }
  bool has = (end > beg);
#pragma unroll
  for (int i = 0; i < 5; ++i) {
    int d = t + 256 * i;
    A[n * D + d] = h_val(lm, nf, n, d) + (has ? m[i] : 0.0f);
  }
}

#define BM 64
#define BN 64
#define BK 16
__global__ __launch_bounds__(256) void gemm_f32_kernel(const float* __restrict__ A,
                                                       const float* __restrict__ W,
                                                       const float* __restrict__ bg,
                                                       const float* __restrict__ lm,
                                                       const float* __restrict__ nf,
                                                       float* __restrict__ C) {
  __shared__ __align__(16) float As[BK][BM + 4];
  __shared__ __align__(16) float Ws[BK][BN + 4];
  int tid = threadIdx.x;
  int tx = tid & 15, ty = tid >> 4;
  int rowBase = blockIdx.y * BM;
  int colBase = blockIdx.x * BN;
  float acc[4][4] = {};
  int ar = tid >> 2;
  int ak = (tid & 3) << 2;
  int wk = tid >> 4;
  int wc = (tid & 15) << 2;
  for (int k0 = 0; k0 < D; k0 += BK) {
    float4 av = *(const float4*)&A[(rowBase + ar) * D + k0 + ak];
    float4 wv = *(const float4*)&W[(k0 + wk) * D + colBase + wc];
    __syncthreads();
    As[ak + 0][ar] = av.x;
    As[ak + 1][ar] = av.y;
    As[ak + 2][ar] = av.z;
    As[ak + 3][ar] = av.w;
    *(float4*)&Ws[wk][wc] = wv;
    __syncthreads();
#pragma unroll
    for (int k = 0; k < BK; ++k) {
      float4 a = *(const float4*)&As[k][ty * 4];
      float4 b = *(const float4*)&Ws[k][tx * 4];
      acc[0][0] += a.x * b.x; acc[0][1] += a.x * b.y; acc[0][2] += a.x * b.z; acc[0][3] += a.x * b.w;
      acc[1][0] += a.y * b.x; acc[1][1] += a.y * b.y; acc[1][2] += a.y * b.z; acc[1][3] += a.y * b.w;
      acc[2][0] += a.z * b.x; acc[2][1] += a.z * b.y; acc[2][2] += a.z * b.z; acc[2][3] += a.z * b.w;
      acc[3][0] += a.w * b.x; acc[3][1] += a.w * b.y; acc[3][2] += a.w * b.z; acc[3][3] += a.w * b.w;
    }
  }
#pragma unroll
  for (int i = 0; i < 4; ++i) {
    int r = rowBase + ty * 4 + i;
#pragma unroll
    for (int j = 0; j < 4; ++j) {
      int cc = colBase + tx * 4 + j;
      C[r * D + cc] = acc[i][j] + bg[cc] + h_val(lm, nf, r, cc);
    }
  }
}

__global__ __launch_bounds__(256) void p_kernel(const float* __restrict__ NO,
                                                const float* __restrict__ Wd,
                                                float* __restrict__ p) {
  int i = blockIdx.x, t = threadIdx.x;
  float acc = 0.f;
#pragma unroll
  for (int j = 0; j < 5; ++j) {
    int k = t + 256 * j;
    acc += NO[i * D + k] * Wd[k];
  }
  __shared__ float s[256];
  s[t] = acc;
  __syncthreads();
  for (int off = 128; off > 0; off >>= 1) {
    if (t < off) s[t] += s[t + off];
    __syncthreads();
  }
  if (t == 0) p[i] = s[0];
}

// =================== launch ===================

extern "C" void kernel_launch(void* const* d_in, const int* in_sizes, int n_in,
                              void* d_out, int out_size, void* d_ws, size_t ws_size,
                              hipStream_t stream) {
  const float* lm = (const float*)d_in[0];
  const float* nf = (const float*)d_in[1];
  const float* ew = (const float*)d_in[2];
  const int* src = (const int*)d_in[3];
  const int* dst = (const int*)d_in[4];
  const int* mask_index = (const int*)d_in[5];
  const float* Wg = (const float*)d_in[6];
  const float* bg = (const float*)d_in[7];
  const float* Wd = (const float*)d_in[8];
  const float* bd = (const float*)d_in[9];
  const float* Wm = (const float*)d_in[10];
  const float* bm = (const float*)d_in[11];
  float* out = (float*)d_out;
  char* w = (char*)d_ws;

  const size_t FAST_WS = 11931664;
  if (ws_size >= FAST_WS) {
    unsigned short* AHi  = (unsigned short*)(w);              // 1,310,720
    unsigned short* ALo  = (unsigned short*)(w + 1310720);    // 1,310,720
    unsigned short* WtHi = (unsigned short*)(w + 2621440);    // 3,276,800
    unsigned short* WtLo = (unsigned short*)(w + 5898240);    // 3,276,800
    float* NO            = (float*)(w + 9175040);             // 2,621,440
    float* p             = (float*)(w + 11796480);            // 2,048
    int* offsets         = (int*)(w + 11798528);              // 2,064
    int* src_s           = (int*)(w + 11800592);              // 65,536
    float* ew_s          = (float*)(w + 11866128);            // 65,536

    convw_kernel<<<dim3(40, 40), 256, 0, stream>>>(Wg, WtHi, WtLo);
    csr_kernel<<<1, 1024, 0, stream>>>(src, dst, ew, offsets, src_s, ew_s);
    neigh_kernel<<<N, 320, 0, stream>>>(lm, nf, offsets, src_s, ew_s, AHi, ALo);
    hipMemsetAsync(p, 0, N * sizeof(float), stream);
    gemm_mfma_kernel<<<dim3(20, 8), 256, 0, stream>>>(AHi, ALo, WtHi, WtLo, bg, Wd,
                                                      lm, nf, NO, p);
    dis4_kernel<<<(N * N / 4) / 256, 256, 0, stream>>>(p, bd, out);
    mask_kernel<<<M, 256, 0, stream>>>(NO, mask_index, Wm, bm, out);
  } else {
    float* A       = (float*)(w);
    float* NO      = (float*)(w + 2621440);
    float* p       = (float*)(w + 5242880);
    int* counts    = (int*)(w + 5244928);
    int* offsets   = (int*)(w + 5246976);
    int* cursor    = (int*)(w + 5249040);
    int* src_s     = (int*)(w + 5251088);
    float* ew_s    = (float*)(w + 5316624);

    hipMemsetAsync(counts, 0, N * sizeof(int), stream);
    hist_kernel<<<E / 256, 256, 0, stream>>>(dst, counts);
    scan_kernel<<<1, 512, 0, stream>>>(counts, offsets, cursor);
    scatter_kernel<<<E / 256, 256, 0, stream>>>(src, dst, ew, cursor, src_s, ew_s);
    neigh_f32_kernel<<<N, 256, 0, stream>>>(lm, nf, offsets, src_s, ew_s, A);
    gemm_f32_kernel<<<dim3(D / BN, N / BM), 256, 0, stream>>>(A, Wg, bg, lm, nf, NO);
    p_kernel<<<N, 256, 0, stream>>>(NO, Wd, p);
    mask_kernel<<<M, 256, 0, stream>>>(NO, mask_index, Wm, bm, out);
    dis4_kernel<<<(N * N / 4) / 256, 256, 0, stream>>>(p, bd, out);
  }
}

// Round 3
// 139.711 us; speedup vs baseline: 1.3739x; 1.1865x over previous
//
#include <hip/hip_runtime.h>
#include <float.h>
#include <math.h>

#define N 512
#define E 16384
#define D 1280
#define LMDIM 1024
#define NFDIM 256
#define M 64

typedef __attribute__((ext_vector_type(8))) short s8v;   // 8 bf16 operand (4 VGPRs)
typedef __attribute__((ext_vector_type(4))) float f4v;   // 4 fp32 acc

// ---------- bf16 helpers ----------
__device__ __forceinline__ unsigned short f2bf(float x) {
  unsigned u = __float_as_uint(x);
  unsigned r = (u + 0x7fffu + ((u >> 16) & 1u)) >> 16;   // RNE
  return (unsigned short)r;
}
__device__ __forceinline__ float bf2f(unsigned short h) {
  return __uint_as_float(((unsigned)h) << 16);
}

// h[i][j] = j < 1024 ? lm[0, i+1, j] : nf[i, j-1024]
__device__ __forceinline__ float h_val(const float* __restrict__ lm,
                                       const float* __restrict__ nf,
                                       int i, int j) {
  return (j < LMDIM) ? lm[(i + 1) * LMDIM + j] : nf[i * NFDIM + (j - LMDIM)];
}
__device__ __forceinline__ float4 h_vec4(const float* __restrict__ lm,
                                         const float* __restrict__ nf,
                                         int i, int t) {  // t = col/4, 0..319
  return (t < 256) ? *(const float4*)&lm[(i + 1) * LMDIM + t * 4]
                   : *(const float4*)&nf[i * NFDIM + (t - 256) * 4];
}

// =================== FAST PATH ===================

// ---- W_g transpose + bf16 hi/lo split: Wt[n][k] = W[k][n] ----
__global__ __launch_bounds__(256) void convw_kernel(const float* __restrict__ W,
                                                    unsigned short* __restrict__ WtHi,
                                                    unsigned short* __restrict__ WtLo) {
  __shared__ float T[32][33];
  int bx = blockIdx.x, by = blockIdx.y;      // bx: n-tile, by: k-tile
  int c = threadIdx.x & 31, r0 = threadIdx.x >> 5;
#pragma unroll
  for (int rr = 0; rr < 4; ++rr) {
    int r = r0 + rr * 8;
    T[r][c] = W[(by * 32 + r) * D + bx * 32 + c];
  }
  __syncthreads();
#pragma unroll
  for (int rr = 0; rr < 4; ++rr) {
    int rn = r0 + rr * 8;                    // n within tile
    float v = T[c][rn];                      // = W[by*32+c][bx*32+rn]
    unsigned short hi = f2bf(v);
    unsigned short lo = f2bf(v - bf2f(hi));
    size_t o = (size_t)(bx * 32 + rn) * D + by * 32 + c;
    WtHi[o] = hi;
    WtLo[o] = lo;
  }
}

// ---- neigh: self-filtered edge scan + segment-max + A = h + neigh (bf16 hi/lo) ----
// Block n filters the full edge list for dst==n in LDS chunks (no CSR build),
// then column-max over matching source rows. Also zeroes p[n] for the gemm's
// fused atomic p-reduction.
#define CHUNK 2048
__global__ __launch_bounds__(320) void neigh_kernel(const float* __restrict__ lm,
                                                    const float* __restrict__ nf,
                                                    const int* __restrict__ src,
                                                    const int* __restrict__ dst,
                                                    const float* __restrict__ ew,
                                                    unsigned short* __restrict__ AHi,
                                                    unsigned short* __restrict__ ALo,
                                                    float* __restrict__ p) {
  __shared__ int s_cnt;
  __shared__ int s_src[CHUNK];
  __shared__ float s_w[CHUNK];
  int n = blockIdx.x;
  int t = threadIdx.x;                       // 0..319, owns cols t*4..t*4+3
  if (t == 0) p[n] = 0.0f;                   // gemm accumulates p with atomics

  float4 m = make_float4(-FLT_MAX, -FLT_MAX, -FLT_MAX, -FLT_MAX);
  bool has = false;

  for (int base = 0; base < E; base += CHUNK) {
    if (t == 0) s_cnt = 0;
    __syncthreads();
    for (int e = base + t; e < base + CHUNK; e += 320) {
      if (dst[e] == n) {
        int pos = atomicAdd(&s_cnt, 1);
        s_src[pos] = src[e];
        s_w[pos] = ew[e];
      }
    }
    __syncthreads();
    int cnt = s_cnt;
    for (int i = 0; i < cnt; ++i) {
      float w = s_w[i];
      float4 v = h_vec4(lm, nf, s_src[i], t);
      m.x = fmaxf(m.x, v.x * w);
      m.y = fmaxf(m.y, v.y * w);
      m.z = fmaxf(m.z, v.z * w);
      m.w = fmaxf(m.w, v.w * w);
    }
    has = has || (cnt > 0);
    __syncthreads();   // protect s_cnt/s_src from next chunk's reset/refill
  }

  float4 hv = h_vec4(lm, nf, n, t);
  float4 a;
  a.x = hv.x + (has ? m.x : 0.0f);
  a.y = hv.y + (has ? m.y : 0.0f);
  a.z = hv.z + (has ? m.z : 0.0f);
  a.w = hv.w + (has ? m.w : 0.0f);
  ushort4 hi, lo;
  hi.x = f2bf(a.x); lo.x = f2bf(a.x - bf2f(hi.x));
  hi.y = f2bf(a.y); lo.y = f2bf(a.y - bf2f(hi.y));
  hi.z = f2bf(a.z); lo.z = f2bf(a.z - bf2f(hi.z));
  hi.w = f2bf(a.w); lo.w = f2bf(a.w - bf2f(hi.w));
  size_t o = (size_t)n * D + t * 4;
  *(ushort4*)&AHi[o] = hi;
  *(ushort4*)&ALo[o] = lo;
}

// ---- MFMA GEMM: NO = A @ W_g + b_g + h ; fused p += NO @ W_d ----
__global__ __launch_bounds__(256) void gemm_mfma_kernel(const unsigned short* __restrict__ AHi,
                                                        const unsigned short* __restrict__ ALo,
                                                        const unsigned short* __restrict__ WtHi,
                                                        const unsigned short* __restrict__ WtLo,
                                                        const float* __restrict__ bg,
                                                        const float* __restrict__ Wd,
                                                        const float* __restrict__ lm,
                                                        const float* __restrict__ nf,
                                                        float* __restrict__ NO,
                                                        float* __restrict__ p) {
  __shared__ __align__(16) short Ah[64][40];
  __shared__ __align__(16) short Al[64][40];
  __shared__ __align__(16) short Bh[64][40];
  __shared__ __align__(16) short Bl[64][40];

  int tid = threadIdx.x;
  int rowBase = blockIdx.y * 64;
  int colBase = blockIdx.x * 64;

  int sr = tid >> 2;                // staging row 0..63
  int sq = (tid & 3) << 3;          // staging k-offset in shorts (0,8,16,24)

  int w = tid >> 6;                 // wave 0..3 -> rows w*16..w*16+15
  int L = tid & 63;
  int q = L >> 4;                   // quad
  int c = L & 15;

  f4v acc[4];
#pragma unroll
  for (int i = 0; i < 4; ++i) acc[i] = (f4v){0.f, 0.f, 0.f, 0.f};

  const size_t aOff = (size_t)(rowBase + sr) * D + sq;
  const size_t bOff = (size_t)(colBase + sr) * D + sq;

  for (int k0 = 0; k0 < D; k0 += 32) {
    s8v va = *(const s8v*)&AHi[aOff + k0];
    s8v vl = *(const s8v*)&ALo[aOff + k0];
    s8v vb = *(const s8v*)&WtHi[bOff + k0];
    s8v vm = *(const s8v*)&WtLo[bOff + k0];
    __syncthreads();
    *(s8v*)&Ah[sr][sq] = va;
    *(s8v*)&Al[sr][sq] = vl;
    *(s8v*)&Bh[sr][sq] = vb;
    *(s8v*)&Bl[sr][sq] = vm;
    __syncthreads();

    s8v ah = *(const s8v*)&Ah[w * 16 + c][q * 8];
    s8v al = *(const s8v*)&Al[w * 16 + c][q * 8];
#pragma unroll
    for (int ct = 0; ct < 4; ++ct) {
      s8v bh = *(const s8v*)&Bh[ct * 16 + c][q * 8];
      s8v bl = *(const s8v*)&Bl[ct * 16 + c][q * 8];
      acc[ct] = __builtin_amdgcn_mfma_f32_16x16x32_bf16(ah, bh, acc[ct], 0, 0, 0);
      acc[ct] = __builtin_amdgcn_mfma_f32_16x16x32_bf16(al, bh, acc[ct], 0, 0, 0);
      acc[ct] = __builtin_amdgcn_mfma_f32_16x16x32_bf16(ah, bl, acc[ct], 0, 0, 0);
    }
  }

  // epilogue: C/D layout row=(q*4+r), col=c within 16x16 tile
  float pp[4] = {0.f, 0.f, 0.f, 0.f};
#pragma unroll
  for (int r = 0; r < 4; ++r) {
    int row = rowBase + w * 16 + q * 4 + r;
#pragma unroll
    for (int ct = 0; ct < 4; ++ct) {
      int col = colBase + ct * 16 + c;
      float v = acc[ct][r] + bg[col] + h_val(lm, nf, row, col);
      NO[(size_t)row * D + col] = v;
      pp[r] += v * Wd[col];
    }
  }
#pragma unroll
  for (int r = 0; r < 4; ++r) {
    pp[r] += __shfl_xor(pp[r], 1);
    pp[r] += __shfl_xor(pp[r], 2);
    pp[r] += __shfl_xor(pp[r], 4);
    pp[r] += __shfl_xor(pp[r], 8);
  }
  if (c == 0) {
#pragma unroll
    for (int r = 0; r < 4; ++r) {
      atomicAdd(&p[rowBase + w * 16 + q * 4 + r], pp[r]);
    }
  }
}

// ---- tail: dis_pred (blocks 0..255, 2 rows each) + mask_pred (blocks 256..319) ----
__global__ __launch_bounds__(256) void tail_kernel(const float* __restrict__ p,
                                                   const float* __restrict__ bd,
                                                   const float* __restrict__ NO,
                                                   const int* __restrict__ mask_index,
                                                   const float* __restrict__ Wm,
                                                   const float* __restrict__ bm,
                                                   float* __restrict__ out) {
  int b = blockIdx.x;
  int t = threadIdx.x;
  if (b < 256) {
    int i = b * 2 + (t >> 7);
    int j4 = (t & 127) * 4;
    float pi = p[i];
    float bias = bd[0];
    float4 pj = *(const float4*)&p[j4];
    float4 o;
    o.x = 1.0f / (1.0f + __expf(-(pj.x - pi + bias)));
    o.y = 1.0f / (1.0f + __expf(-(pj.y - pi + bias)));
    o.z = 1.0f / (1.0f + __expf(-(pj.z - pi + bias)));
    o.w = 1.0f / (1.0f + __expf(-(pj.w - pi + bias)));
    *(float4*)&out[(size_t)i * N + j4] = o;
  } else {
    int mb = b - 256;               // 0..63
    int row = mask_index[mb];
    float a0 = 0.f, a1 = 0.f;
#pragma unroll
    for (int j = 0; j < 5; ++j) {
      int k = t + 256 * j;
      float v = NO[(size_t)row * D + k];
      a0 += v * Wm[k * 2 + 0];
      a1 += v * Wm[k * 2 + 1];
    }
    __shared__ float s0[256], s1[256];
    s0[t] = a0;
    s1[t] = a1;
    __syncthreads();
    for (int off = 128; off > 0; off >>= 1) {
      if (t < off) {
        s0[t] += s0[t + off];
        s1[t] += s1[t + off];
      }
      __syncthreads();
    }
    if (t == 0) {
      out[(size_t)N * N + mb * 2 + 0] = tanhf(s0[0] + bm[0]);
      out[(size_t)N * N + mb * 2 + 1] = tanhf(s1[0] + bm[1]);
    }
  }
}

// =================== FALLBACK PATH (fp32, needs only 5.4 MB ws) ===================

__global__ __launch_bounds__(256) void hist_kernel(const int* __restrict__ dst,
                                                   int* __restrict__ counts) {
  int e = blockIdx.x * 256 + threadIdx.x;
  atomicAdd(&counts[dst[e]], 1);
}

__global__ __launch_bounds__(512) void scan_kernel(const int* __restrict__ counts,
                                                   int* __restrict__ offsets,
                                                   int* __restrict__ cursor) {
  __shared__ int s[N];
  int t = threadIdx.x;
  int cc = counts[t];
  s[t] = cc;
  __syncthreads();
  for (int off = 1; off < N; off <<= 1) {
    int v = (t >= off) ? s[t - off] : 0;
    __syncthreads();
    s[t] += v;
    __syncthreads();
  }
  offsets[t + 1] = s[t];
  if (t == 0) offsets[0] = 0;
  cursor[t] = s[t] - cc;
}

__global__ __launch_bounds__(256) void scatter_kernel(const int* __restrict__ src,
                                                      const int* __restrict__ dst,
                                                      const float* __restrict__ ew,
                                                      int* __restrict__ cursor,
                                                      int* __restrict__ src_s,
                                                      float* __restrict__ ew_s) {
  int e = blockIdx.x * 256 + threadIdx.x;
  int d = dst[e];
  int pos = atomicAdd(&cursor[d], 1);
  src_s[pos] = src[e];
  ew_s[pos] = ew[e];
}

__global__ __launch_bounds__(256) void neigh_f32_kernel(const float* __restrict__ lm,
                                                        const float* __restrict__ nf,
                                                        const int* __restrict__ offsets,
                                                        const int* __restrict__ src_s,
                                                        const float* __restrict__ ew_s,
                                                        float* __restrict__ A) {
  int n = blockIdx.x;
  int t = threadIdx.x;
  int beg = offsets[n], end = offsets[n + 1];
  float m[5];
#pragma unroll
  for (int i = 0; i < 5; ++i) m[i] = -FLT_MAX;
  for (int e = beg; e < end; ++e) {
    int s = src_s[e];
    float w = ew_s[e];
#pragma unroll
    for (int i = 0; i < 5; ++i) {
      int d = t + 256 * i;
      m[i] = fmaxf(m[i], h_val(lm, nf, s, d) * w);
    }
  }
  bool has = (end > beg);
#pragma unroll
  for (int i = 0; i < 5; ++i) {
    int d = t + 256 * i;
    A[n * D + d] = h_val(lm, nf, n, d) + (has ? m[i] : 0.0f);
  }
}

#define BM 64
#define BN 64
#define BK 16
__global__ __launch_bounds__(256) void gemm_f32_kernel(const float* __restrict__ A,
                                                       const float* __restrict__ W,
                                                       const float* __restrict__ bg,
                                                       const float* __restrict__ lm,
                                                       const float* __restrict__ nf,
                                                       float* __restrict__ C) {
  __shared__ __align__(16) float As[BK][BM + 4];
  __shared__ __align__(16) float Ws[BK][BN + 4];
  int tid = threadIdx.x;
  int tx = tid & 15, ty = tid >> 4;
  int rowBase = blockIdx.y * BM;
  int colBase = blockIdx.x * BN;
  float acc[4][4] = {};
  int ar = tid >> 2;
  int ak = (tid & 3) << 2;
  int wk = tid >> 4;
  int wc = (tid & 15) << 2;
  for (int k0 = 0; k0 < D; k0 += BK) {
    float4 av = *(const float4*)&A[(rowBase + ar) * D + k0 + ak];
    float4 wv = *(const float4*)&W[(k0 + wk) * D + colBase + wc];
    __syncthreads();
    As[ak + 0][ar] = av.x;
    As[ak + 1][ar] = av.y;
    As[ak + 2][ar] = av.z;
    As[ak + 3][ar] = av.w;
    *(float4*)&Ws[wk][wc] = wv;
    __syncthreads();
#pragma unroll
    for (int k = 0; k < BK; ++k) {
      float4 a = *(const float4*)&As[k][ty * 4];
      float4 b = *(const float4*)&Ws[k][tx * 4];
      acc[0][0] += a.x * b.x; acc[0][1] += a.x * b.y; acc[0][2] += a.x * b.z; acc[0][3] += a.x * b.w;
      acc[1][0] += a.y * b.x; acc[1][1] += a.y * b.y; acc[1][2] += a.y * b.z; acc[1][3] += a.y * b.w;
      acc[2][0] += a.z * b.x; acc[2][1] += a.z * b.y; acc[2][2] += a.z * b.z; acc[2][3] += a.z * b.w;
      acc[3][0] += a.w * b.x; acc[3][1] += a.w * b.y; acc[3][2] += a.w * b.z; acc[3][3] += a.w * b.w;
    }
  }
#pragma unroll
  for (int i = 0; i < 4; ++i) {
    int r = rowBase + ty * 4 + i;
#pragma unroll
    for (int j = 0; j < 4; ++j) {
      int cc = colBase + tx * 4 + j;
      C[r * D + cc] = acc[i][j] + bg[cc] + h_val(lm, nf, r, cc);
    }
  }
}

__global__ __launch_bounds__(256) void p_kernel(const float* __restrict__ NO,
                                                const float* __restrict__ Wd,
                                                float* __restrict__ p) {
  int i = blockIdx.x, t = threadIdx.x;
  float acc = 0.f;
#pragma unroll
  for (int j = 0; j < 5; ++j) {
    int k = t + 256 * j;
    acc += NO[i * D + k] * Wd[k];
  }
  __shared__ float s[256];
  s[t] = acc;
  __syncthreads();
  for (int off = 128; off > 0; off >>= 1) {
    if (t < off) s[t] += s[t + off];
    __syncthreads();
  }
  if (t == 0) p[i] = s[0];
}

// =================== launch ===================

extern "C" void kernel_launch(void* const* d_in, const int* in_sizes, int n_in,
                              void* d_out, int out_size, void* d_ws, size_t ws_size,
                              hipStream_t stream) {
  const float* lm = (const float*)d_in[0];
  const float* nf = (const float*)d_in[1];
  const float* ew = (const float*)d_in[2];
  const int* src = (const int*)d_in[3];
  const int* dst = (const int*)d_in[4];
  const int* mask_index = (const int*)d_in[5];
  const float* Wg = (const float*)d_in[6];
  const float* bg = (const float*)d_in[7];
  const float* Wd = (const float*)d_in[8];
  const float* bd = (const float*)d_in[9];
  const float* Wm = (const float*)d_in[10];
  const float* bm = (const float*)d_in[11];
  float* out = (float*)d_out;
  char* w = (char*)d_ws;

  const size_t FAST_WS = 11800000;
  if (ws_size >= FAST_WS) {
    unsigned short* AHi  = (unsigned short*)(w);              // 1,310,720
    unsigned short* ALo  = (unsigned short*)(w + 1310720);    // 1,310,720
    unsigned short* WtHi = (unsigned short*)(w + 2621440);    // 3,276,800
    unsigned short* WtLo = (unsigned short*)(w + 5898240);    // 3,276,800
    float* NO            = (float*)(w + 9175040);             // 2,621,440
    float* p             = (float*)(w + 11796480);            // 2,048

    convw_kernel<<<dim3(40, 40), 256, 0, stream>>>(Wg, WtHi, WtLo);
    neigh_kernel<<<N, 320, 0, stream>>>(lm, nf, src, dst, ew, AHi, ALo, p);
    gemm_mfma_kernel<<<dim3(20, 8), 256, 0, stream>>>(AHi, ALo, WtHi, WtLo, bg, Wd,
                                                      lm, nf, NO, p);
    tail_kernel<<<320, 256, 0, stream>>>(p, bd, NO, mask_index, Wm, bm, out);
  } else {
    float* A       = (float*)(w);
    float* NO      = (float*)(w + 2621440);
    float* p       = (float*)(w + 5242880);
    int* counts    = (int*)(w + 5244928);
    int* offsets   = (int*)(w + 5246976);
    int* cursor    = (int*)(w + 5249040);
    int* src_s     = (int*)(w + 5251088);
    float* ew_s    = (float*)(w + 5316624);

    hipMemsetAsync(counts, 0, N * sizeof(int), stream);
    hist_kernel<<<E / 256, 256, 0, stream>>>(dst, counts);
    scan_kernel<<<1, 512, 0, stream>>>(counts, offsets, cursor);
    scatter_kernel<<<E / 256, 256, 0, stream>>>(src, dst, ew, cursor, src_s, ew_s);
    neigh_f32_kernel<<<N, 256, 0, stream>>>(lm, nf, offsets, src_s, ew_s, A);
    gemm_f32_kernel<<<dim3(D / BN, N / BM), 256, 0, stream>>>(A, Wg, bg, lm, nf, NO);
    p_kernel<<<N, 256, 0, stream>>>(NO, Wd, p);
    tail_kernel<<<320, 256, 0, stream>>>(p, bd, NO, mask_index, Wm, bm, out);
  }
}